// Round 1
// baseline (311.262 us; speedup 1.0000x reference)
//
#include <hip/hip_runtime.h>
#include <hip/hip_bf16.h>
#include <stdint.h>

#define HEADS 16
#define HD 64
#define BATCH 2
#define SEQ 2048
#define NDIM 1024
#define MROWS (BATCH * SEQ)   // 4096

typedef __attribute__((ext_vector_type(8))) __bf16 bf16x8;
typedef __attribute__((ext_vector_type(4))) __bf16 bf16x4;
typedef __attribute__((ext_vector_type(4))) float f32x4;

#define LOG2E 1.4426950408889634f

// async global->LDS, 16B per lane. dest must be wave-uniform base + lane*16.
#define GLDS16(g, l)                                                          \
  __builtin_amdgcn_global_load_lds(                                           \
      (const __attribute__((address_space(1))) unsigned int*)(g),             \
      (__attribute__((address_space(3))) unsigned int*)(l), 16, 0, 0)

// ---------------------------------------------------------------- f32 -> bf16
__global__ void cvt_kernel(const float* __restrict__ in, __bf16* __restrict__ out) {
  size_t i = ((size_t)blockIdx.x * 256 + threadIdx.x) * 4;
  const float4 v = *(const float4*)(in + i);
  bf16x4 o = {(__bf16)v.x, (__bf16)v.y, (__bf16)v.z, (__bf16)v.w};
  *(bf16x4*)(out + i) = o;
}

// ------------------------------------------------- GEMM core: C = A @ B^T
// A[M,1024], B[N,1024] row-major bf16. 128x128 tile, BK=32, 256 thr = 4 waves
// (2x2), each wave 64x64 = 4x4 frags of 16x16x32 MFMA. Single-buffered LDS.
__device__ __forceinline__ void gemm_core_1024(const __bf16* __restrict__ A,
                                               const __bf16* __restrict__ B,
                                               int m0, int n0,
                                               __bf16* ldsA, __bf16* ldsB,
                                               f32x4 acc[4][4]) {
  const int t = threadIdx.x;
  const int lane = t & 63;
  const int llo = lane & 15, lhi = lane >> 4;
  const int wid = t >> 6;
  const int wrow = (wid >> 1) * 64;
  const int wcol = (wid & 1) * 64;

  const int rA = t >> 2;          // 0..63  (row within tile, first half)
  const int cA = (t & 3) * 8;     // 0,8,16,24 (col in elems)

  char* lA = (char*)ldsA;
  char* lB = (char*)ldsB;

#pragma unroll
  for (int mf = 0; mf < 4; ++mf)
#pragma unroll
    for (int nf = 0; nf < 4; ++nf)
      acc[mf][nf] = (f32x4){0.f, 0.f, 0.f, 0.f};

  for (int k0 = 0; k0 < 1024; k0 += 32) {
    __syncthreads();   // previous iter's reads done before overwrite
    GLDS16(A + (size_t)(m0 + rA) * 1024 + k0 + cA,      lA + t * 16);
    GLDS16(A + (size_t)(m0 + 64 + rA) * 1024 + k0 + cA, lA + (t + 256) * 16);
    GLDS16(B + (size_t)(n0 + rA) * 1024 + k0 + cA,      lB + t * 16);
    GLDS16(B + (size_t)(n0 + 64 + rA) * 1024 + k0 + cA, lB + (t + 256) * 16);
    __syncthreads();   // compiler drains vmcnt before barrier

    bf16x8 af[4], bfr[4];
#pragma unroll
    for (int mf = 0; mf < 4; ++mf)
      af[mf] = *(const bf16x8*)(lA + ((wrow + mf * 16 + llo) * 32 + lhi * 8) * 2);
#pragma unroll
    for (int nf = 0; nf < 4; ++nf)
      bfr[nf] = *(const bf16x8*)(lB + ((wcol + nf * 16 + llo) * 32 + lhi * 8) * 2);
#pragma unroll
    for (int mf = 0; mf < 4; ++mf)
#pragma unroll
      for (int nf = 0; nf < 4; ++nf)
        acc[mf][nf] = __builtin_amdgcn_mfma_f32_16x16x32_bf16(af[mf], bfr[nf],
                                                              acc[mf][nf], 0, 0, 0);
  }
}

// --------------------------------------------------------- fused QKV GEMM
// grid (32, 24): y<8 -> Q, y<16 -> K, else V. Q scaled by 0.125 (1/sqrt(hd)).
// Q,K stored [b*16+h][s][d]; V stored transposed [b*16+h][d][s].
__global__ __launch_bounds__(256, 2)
void qkv_gemm_kernel(const __bf16* __restrict__ Xq, const __bf16* __restrict__ Xk,
                     const __bf16* __restrict__ Xv, const __bf16* __restrict__ Wq,
                     const __bf16* __restrict__ Wk, const __bf16* __restrict__ Wv,
                     const float* __restrict__ bq, const float* __restrict__ bk,
                     const float* __restrict__ bv, __bf16* __restrict__ Qh,
                     __bf16* __restrict__ Kh, __bf16* __restrict__ Vt) {
  __shared__ __align__(16) __bf16 ldsA[128 * 32];
  __shared__ __align__(16) __bf16 ldsB[128 * 32];

  const int m0 = blockIdx.x * 128;
  const int mat = blockIdx.y >> 3;
  const int n0 = (blockIdx.y & 7) * 128;

  const __bf16* A = (mat == 0) ? Xq : (mat == 1) ? Xk : Xv;
  const __bf16* B = (mat == 0) ? Wq : (mat == 1) ? Wk : Wv;
  const float* bias = (mat == 0) ? bq : (mat == 1) ? bk : bv;

  f32x4 acc[4][4];
  gemm_core_1024(A, B, m0, n0, ldsA, ldsB, acc);

  const int t = threadIdx.x;
  const int lane = t & 63;
  const int llo = lane & 15, lhi = lane >> 4;
  const int wid = t >> 6;
  const int wrow = (wid >> 1) * 64;
  const int wcol = (wid & 1) * 64;

#pragma unroll
  for (int nf = 0; nf < 4; ++nf) {
    const int cfull = n0 + wcol + nf * 16 + llo;  // 0..1023
    const int h = cfull >> 6, d = cfull & 63;
    const float bb = bias[cfull];
#pragma unroll
    for (int mf = 0; mf < 4; ++mf) {
      const int row0 = m0 + wrow + mf * 16 + lhi * 4;  // 4 consecutive rows
      const int b = row0 >> 11;
      const int s0 = row0 & 2047;
      if (mat == 2) {  // V transposed: 4 consecutive s -> one 8B store
        bf16x4 pk;
#pragma unroll
        for (int j = 0; j < 4; ++j) pk[j] = (__bf16)(acc[mf][nf][j] + bb);
        *(bf16x4*)(Vt + ((size_t)(b * HEADS + h) * HD + d) * SEQ + s0) = pk;
      } else {
#pragma unroll
        for (int j = 0; j < 4; ++j) {
          float v = acc[mf][nf][j] + bb;
          size_t addr = ((size_t)(b * HEADS + h) * SEQ + s0 + j) * HD + d;
          if (mat == 0)
            Qh[addr] = (__bf16)(v * 0.125f);
          else
            Kh[addr] = (__bf16)v;
        }
      }
    }
  }
}

// --------------------------------------------------------------- attention
// grid (S/64=32, B*H=32), 256 thr = 4 waves; wave w owns q rows q0+w*16..+15.
// K,V read from global (L2-resident); P via per-wave swizzled LDS buffer.
__global__ __launch_bounds__(256, 2)
void attn_kernel(const __bf16* __restrict__ Qh, const __bf16* __restrict__ Kh,
                 const __bf16* __restrict__ Vt, __bf16* __restrict__ O,
                 const int* __restrict__ causal_flag) {
  __shared__ __align__(16) __bf16 ldsP[4][16 * 64];

  const int t = threadIdx.x;
  const int lane = t & 63;
  const int llo = lane & 15, lhi = lane >> 4;
  const int w = t >> 6;
  const int bh = blockIdx.y;
  const int q0 = blockIdx.x * 64;
  const int qw = q0 + w * 16;
  const int causal = causal_flag[0];

  const __bf16* Qb = Qh + (size_t)bh * SEQ * HD;
  const __bf16* Kb = Kh + (size_t)bh * SEQ * HD;
  const __bf16* Vb = Vt + (size_t)bh * HD * SEQ;

  bf16x8 aQ[2];
#pragma unroll
  for (int ks = 0; ks < 2; ++ks)
    aQ[ks] = *(const bf16x8*)(Qb + (size_t)(qw + llo) * HD + ks * 32 + lhi * 8);

  float mrun[4], lrun[4];
  f32x4 accO[4];
#pragma unroll
  for (int j = 0; j < 4; ++j) { mrun[j] = -1e30f; lrun[j] = 0.f; }
#pragma unroll
  for (int nf = 0; nf < 4; ++nf) accO[nf] = (f32x4){0.f, 0.f, 0.f, 0.f};

  __bf16* Pw = &ldsP[w][0];
  const int tmax = causal ? blockIdx.x : (SEQ / 64 - 1);

  for (int tkv = 0; tkv <= tmax; ++tkv) {
    const int k0 = tkv * 64;
    // ---- S = Q @ K^T  (Q pre-scaled)
    f32x4 s[4];
#pragma unroll
    for (int nf = 0; nf < 4; ++nf) {
      s[nf] = (f32x4){0.f, 0.f, 0.f, 0.f};
#pragma unroll
      for (int ks = 0; ks < 2; ++ks) {
        bf16x8 bK = *(const bf16x8*)(Kb + (size_t)(k0 + nf * 16 + llo) * HD +
                                     ks * 32 + lhi * 8);
        s[nf] = __builtin_amdgcn_mfma_f32_16x16x32_bf16(aQ[ks], bK, s[nf], 0, 0, 0);
      }
    }
    // ---- causal mask on the diagonal tile
    if (causal && tkv == blockIdx.x) {
#pragma unroll
      for (int nf = 0; nf < 4; ++nf) {
        const int kv = k0 + nf * 16 + llo;
#pragma unroll
        for (int j = 0; j < 4; ++j)
          if (kv > qw + lhi * 4 + j) s[nf][j] = -1e30f;
      }
    }
    // ---- online softmax (rows = lhi*4+j, cols spread over 16 lanes x 4 frags)
    float rm[4];
#pragma unroll
    for (int j = 0; j < 4; ++j)
      rm[j] = fmaxf(fmaxf(s[0][j], s[1][j]), fmaxf(s[2][j], s[3][j]));
#pragma unroll
    for (int xm = 1; xm < 16; xm <<= 1)
#pragma unroll
      for (int j = 0; j < 4; ++j) rm[j] = fmaxf(rm[j], __shfl_xor(rm[j], xm, 64));

    float corr[4];
#pragma unroll
    for (int j = 0; j < 4; ++j) {
      const float mn = fmaxf(mrun[j], rm[j]);
      corr[j] = exp2f((mrun[j] - mn) * LOG2E);
      mrun[j] = mn;
    }
    float rs[4] = {0.f, 0.f, 0.f, 0.f};
#pragma unroll
    for (int nf = 0; nf < 4; ++nf)
#pragma unroll
      for (int j = 0; j < 4; ++j) {
        const float p = exp2f((s[nf][j] - mrun[j]) * LOG2E);
        s[nf][j] = p;
        rs[j] += p;
      }
#pragma unroll
    for (int xm = 1; xm < 16; xm <<= 1)
#pragma unroll
      for (int j = 0; j < 4; ++j) rs[j] += __shfl_xor(rs[j], xm, 64);
#pragma unroll
    for (int j = 0; j < 4; ++j) lrun[j] = lrun[j] * corr[j] + rs[j];
#pragma unroll
    for (int nf = 0; nf < 4; ++nf)
#pragma unroll
      for (int j = 0; j < 4; ++j) accO[nf][j] *= corr[j];

    // ---- P -> LDS (XOR swizzle kills 16-way conflict on the A-frag reads)
#pragma unroll
    for (int nf = 0; nf < 4; ++nf)
#pragma unroll
      for (int j = 0; j < 4; ++j) {
        const int r = lhi * 4 + j;
        const int c = (nf * 16 + llo) ^ ((r & 7) << 3);
        Pw[r * 64 + c] = (__bf16)s[nf][j];
      }
    // ---- O += P @ V   (Vt rows contiguous in kv -> 16B loads)
#pragma unroll
    for (int ks2 = 0; ks2 < 2; ++ks2) {
      const int ckv = (ks2 * 32 + lhi * 8) ^ ((llo & 7) << 3);
      bf16x8 aP = *(const bf16x8*)(Pw + llo * 64 + ckv);
#pragma unroll
      for (int nf = 0; nf < 4; ++nf) {
        bf16x8 bV = *(const bf16x8*)(Vb + (size_t)(nf * 16 + llo) * SEQ + k0 +
                                     ks2 * 32 + lhi * 8);
        accO[nf] = __builtin_amdgcn_mfma_f32_16x16x32_bf16(aP, bV, accO[nf], 0, 0, 0);
      }
    }
  }

  // ---- normalize + store O as [b,s,h,d] (row-major 4096x1024)
  const int b = bh >> 4, h = bh & 15;
#pragma unroll
  for (int j = 0; j < 4; ++j) {
    const float inv = 1.f / lrun[j];
    const int srow = qw + lhi * 4 + j;
#pragma unroll
    for (int nf = 0; nf < 4; ++nf)
      O[((size_t)(b * SEQ + srow) * HEADS + h) * HD + nf * 16 + llo] =
          (__bf16)(accO[nf][j] * inv);
  }
}

// ---------------------------------------------------------- output projection
__global__ __launch_bounds__(256, 2)
void out_gemm_kernel(const __bf16* __restrict__ Oin, const __bf16* __restrict__ Wo,
                     const float* __restrict__ bo, float* __restrict__ out) {
  __shared__ __align__(16) __bf16 ldsA[128 * 32];
  __shared__ __align__(16) __bf16 ldsB[128 * 32];
  const int m0 = blockIdx.x * 128;
  const int n0 = blockIdx.y * 128;

  f32x4 acc[4][4];
  gemm_core_1024(Oin, Wo, m0, n0, ldsA, ldsB, acc);

  const int t = threadIdx.x;
  const int lane = t & 63;
  const int llo = lane & 15, lhi = lane >> 4;
  const int wid = t >> 6;
  const int wrow = (wid >> 1) * 64;
  const int wcol = (wid & 1) * 64;

#pragma unroll
  for (int nf = 0; nf < 4; ++nf) {
    const int col = n0 + wcol + nf * 16 + llo;
    const float bb = bo[col];
#pragma unroll
    for (int mf = 0; mf < 4; ++mf)
#pragma unroll
      for (int j = 0; j < 4; ++j) {
        const int row = m0 + wrow + mf * 16 + lhi * 4 + j;
        out[(size_t)row * NDIM + col] = acc[mf][nf][j] + bb;
      }
  }
}

// ------------------------------------------------------------------- launch
extern "C" void kernel_launch(void* const* d_in, const int* in_sizes, int n_in,
                              void* d_out, int out_size, void* d_ws, size_t ws_size,
                              hipStream_t stream) {
  const float* Q_in = (const float*)d_in[0];
  const float* K_in = (const float*)d_in[1];
  const float* V_in = (const float*)d_in[2];
  const float* Wq = (const float*)d_in[3];
  const float* bq = (const float*)d_in[4];
  const float* Wk = (const float*)d_in[5];
  const float* bk = (const float*)d_in[6];
  const float* Wv = (const float*)d_in[7];
  const float* bv = (const float*)d_in[8];
  const float* Wo = (const float*)d_in[9];
  const float* bo = (const float*)d_in[10];
  const int* causal = (const int*)d_in[11];
  float* out = (float*)d_out;

  char* p = (char*)d_ws;
  const size_t SZ_X = (size_t)MROWS * NDIM * 2;  // 8 MB
  const size_t SZ_W = (size_t)NDIM * NDIM * 2;   // 2 MB
  __bf16* bXq = (__bf16*)p; p += SZ_X;
  __bf16* bXk = (__bf16*)p; p += SZ_X;
  __bf16* bXv = (__bf16*)p; p += SZ_X;
  __bf16* bWq = (__bf16*)p; p += SZ_W;
  __bf16* bWk = (__bf16*)p; p += SZ_W;
  __bf16* bWv = (__bf16*)p; p += SZ_W;
  __bf16* bWo = (__bf16*)p; p += SZ_W;
  __bf16* Qh  = (__bf16*)p; p += SZ_X;
  __bf16* Kh  = (__bf16*)p; p += SZ_X;
  __bf16* Vt  = (__bf16*)p; p += SZ_X;
  __bf16* Obf = (__bf16*)p; p += SZ_X;

  // f32 -> bf16 (4 elems/thread)
  const int XB = MROWS * NDIM / 1024;  // 4096 blocks
  const int WB = NDIM * NDIM / 1024;   // 1024 blocks
  cvt_kernel<<<XB, 256, 0, stream>>>(Q_in, bXq);
  cvt_kernel<<<XB, 256, 0, stream>>>(K_in, bXk);
  cvt_kernel<<<XB, 256, 0, stream>>>(V_in, bXv);
  cvt_kernel<<<WB, 256, 0, stream>>>(Wq, bWq);
  cvt_kernel<<<WB, 256, 0, stream>>>(Wk, bWk);
  cvt_kernel<<<WB, 256, 0, stream>>>(Wv, bWv);
  cvt_kernel<<<WB, 256, 0, stream>>>(Wo, bWo);

  qkv_gemm_kernel<<<dim3(32, 24), 256, 0, stream>>>(bXq, bXk, bXv, bWq, bWk, bWv,
                                                    bq, bk, bv, Qh, Kh, Vt);
  attn_kernel<<<dim3(SEQ / 64, BATCH * HEADS), 256, 0, stream>>>(Qh, Kh, Vt, Obf,
                                                                 causal);
  out_gemm_kernel<<<dim3(32, 8), 256, 0, stream>>>(Obf, bWo, bo, out);
}

// Round 2
// 133.456 us; speedup vs baseline: 2.3323x; 2.3323x over previous
//
#include <hip/hip_runtime.h>
#include <hip/hip_bf16.h>
#include <stdint.h>

#define HEADS 16
#define HD 64
#define BATCH 2
#define SEQ 2048
#define NDIM 1024
#define MROWS (BATCH * SEQ)   // 4096

typedef __attribute__((ext_vector_type(8))) __bf16 bf16x8;
typedef __attribute__((ext_vector_type(4))) __bf16 bf16x4;
typedef __attribute__((ext_vector_type(4))) float f32x4;

#define LOG2E 1.4426950408889634f

// async global->LDS, 16B per lane. dest must be wave-uniform base + lane*16.
#define GLDS16(g, l)                                                          \
  __builtin_amdgcn_global_load_lds(                                           \
      (const __attribute__((address_space(1))) unsigned int*)(g),             \
      (__attribute__((address_space(3))) unsigned int*)(l), 16, 0, 0)

// ---------------------------------------------------------------- f32 -> bf16
__global__ void cvt3_kernel(const float* __restrict__ a0, const float* __restrict__ a1,
                            const float* __restrict__ a2, __bf16* __restrict__ o0,
                            __bf16* __restrict__ o1, __bf16* __restrict__ o2) {
  const float* in = (blockIdx.y == 0) ? a0 : (blockIdx.y == 1) ? a1 : a2;
  __bf16* out = (blockIdx.y == 0) ? o0 : (blockIdx.y == 1) ? o1 : o2;
  size_t i = ((size_t)blockIdx.x * 256 + threadIdx.x) * 4;
  const float4 v = *(const float4*)(in + i);
  bf16x4 o = {(__bf16)v.x, (__bf16)v.y, (__bf16)v.z, (__bf16)v.w};
  *(bf16x4*)(out + i) = o;
}

__global__ void cvt4_kernel(const float* __restrict__ a0, const float* __restrict__ a1,
                            const float* __restrict__ a2, const float* __restrict__ a3,
                            __bf16* __restrict__ o0, __bf16* __restrict__ o1,
                            __bf16* __restrict__ o2, __bf16* __restrict__ o3) {
  const float* in = (blockIdx.y == 0) ? a0 : (blockIdx.y == 1) ? a1
                    : (blockIdx.y == 2) ? a2 : a3;
  __bf16* out = (blockIdx.y == 0) ? o0 : (blockIdx.y == 1) ? o1
                : (blockIdx.y == 2) ? o2 : o3;
  size_t i = ((size_t)blockIdx.x * 256 + threadIdx.x) * 4;
  const float4 v = *(const float4*)(in + i);
  bf16x4 o = {(__bf16)v.x, (__bf16)v.y, (__bf16)v.z, (__bf16)v.w};
  *(bf16x4*)(out + i) = o;
}

// ------------------------------------------------- GEMM core: C = A @ B^T
// A[M,1024], B[N,1024] row-major bf16. 128x128 tile, BK=32, 256 thr = 4 waves
// (2x2), each wave 64x64 = 4x4 frags of 16x16x32 MFMA. Single-buffered LDS.
__device__ __forceinline__ void gemm_core_1024(const __bf16* __restrict__ A,
                                               const __bf16* __restrict__ B,
                                               int m0, int n0,
                                               __bf16* ldsA, __bf16* ldsB,
                                               f32x4 acc[4][4]) {
  const int t = threadIdx.x;
  const int lane = t & 63;
  const int llo = lane & 15, lhi = lane >> 4;
  const int wid = t >> 6;
  const int wrow = (wid >> 1) * 64;
  const int wcol = (wid & 1) * 64;

  const int rA = t >> 2;          // 0..63
  const int cA = (t & 3) * 8;     // 0,8,16,24

  char* lA = (char*)ldsA;
  char* lB = (char*)ldsB;

#pragma unroll
  for (int mf = 0; mf < 4; ++mf)
#pragma unroll
    for (int nf = 0; nf < 4; ++nf)
      acc[mf][nf] = (f32x4){0.f, 0.f, 0.f, 0.f};

  for (int k0 = 0; k0 < 1024; k0 += 32) {
    __syncthreads();
    GLDS16(A + (size_t)(m0 + rA) * 1024 + k0 + cA,      lA + t * 16);
    GLDS16(A + (size_t)(m0 + 64 + rA) * 1024 + k0 + cA, lA + (t + 256) * 16);
    GLDS16(B + (size_t)(n0 + rA) * 1024 + k0 + cA,      lB + t * 16);
    GLDS16(B + (size_t)(n0 + 64 + rA) * 1024 + k0 + cA, lB + (t + 256) * 16);
    __syncthreads();

    bf16x8 af[4], bfr[4];
#pragma unroll
    for (int mf = 0; mf < 4; ++mf)
      af[mf] = *(const bf16x8*)(lA + ((wrow + mf * 16 + llo) * 32 + lhi * 8) * 2);
#pragma unroll
    for (int nf = 0; nf < 4; ++nf)
      bfr[nf] = *(const bf16x8*)(lB + ((wcol + nf * 16 + llo) * 32 + lhi * 8) * 2);
#pragma unroll
    for (int mf = 0; mf < 4; ++mf)
#pragma unroll
      for (int nf = 0; nf < 4; ++nf)
        acc[mf][nf] = __builtin_amdgcn_mfma_f32_16x16x32_bf16(af[mf], bfr[nf],
                                                              acc[mf][nf], 0, 0, 0);
  }
}

// --------------------------------------------------------- fused QKV GEMM
__global__ __launch_bounds__(256, 2)
void qkv_gemm_kernel(const __bf16* __restrict__ Xq, const __bf16* __restrict__ Xk,
                     const __bf16* __restrict__ Xv, const __bf16* __restrict__ Wq,
                     const __bf16* __restrict__ Wk, const __bf16* __restrict__ Wv,
                     const float* __restrict__ bq, const float* __restrict__ bk,
                     const float* __restrict__ bv, __bf16* __restrict__ Qh,
                     __bf16* __restrict__ Kh, __bf16* __restrict__ Vt) {
  __shared__ __align__(16) __bf16 ldsA[128 * 32];
  __shared__ __align__(16) __bf16 ldsB[128 * 32];

  const int m0 = blockIdx.x * 128;
  const int mat = blockIdx.y >> 3;
  const int n0 = (blockIdx.y & 7) * 128;

  const __bf16* A = (mat == 0) ? Xq : (mat == 1) ? Xk : Xv;
  const __bf16* B = (mat == 0) ? Wq : (mat == 1) ? Wk : Wv;
  const float* bias = (mat == 0) ? bq : (mat == 1) ? bk : bv;

  f32x4 acc[4][4];
  gemm_core_1024(A, B, m0, n0, ldsA, ldsB, acc);

  const int t = threadIdx.x;
  const int lane = t & 63;
  const int llo = lane & 15, lhi = lane >> 4;
  const int wid = t >> 6;
  const int wrow = (wid >> 1) * 64;
  const int wcol = (wid & 1) * 64;

#pragma unroll
  for (int nf = 0; nf < 4; ++nf) {
    const int cfull = n0 + wcol + nf * 16 + llo;
    const int h = cfull >> 6, d = cfull & 63;
    const float bb = bias[cfull];
#pragma unroll
    for (int mf = 0; mf < 4; ++mf) {
      const int row0 = m0 + wrow + mf * 16 + lhi * 4;
      const int b = row0 >> 11;
      const int s0 = row0 & 2047;
      if (mat == 2) {
        bf16x4 pk;
#pragma unroll
        for (int j = 0; j < 4; ++j) pk[j] = (__bf16)(acc[mf][nf][j] + bb);
        *(bf16x4*)(Vt + ((size_t)(b * HEADS + h) * HD + d) * SEQ + s0) = pk;
      } else {
#pragma unroll
        for (int j = 0; j < 4; ++j) {
          float v = acc[mf][nf][j] + bb;
          size_t addr = ((size_t)(b * HEADS + h) * SEQ + s0 + j) * HD + d;
          if (mat == 0)
            Qh[addr] = (__bf16)(v * 0.125f);
          else
            Kh[addr] = (__bf16)v;
        }
      }
    }
  }
}

// --------------------------------------------------------------- attention
// grid (16, 32), 256 thr = 4 waves. Block handles q-tile pair (x, 31-x) ->
// uniform 33 kv-iters (causal). Swapped QK^T (mfma(K,Q)) -> lane-local
// softmax rows. K/V double-buffered in LDS via global_load_lds with
// pre-swizzled source (XOR (row&7)<<4); conflict-free ds_read_b128.
__global__ __launch_bounds__(256, 2)
void attn_kernel(const __bf16* __restrict__ Qh, const __bf16* __restrict__ Kh,
                 const __bf16* __restrict__ Vt, __bf16* __restrict__ O,
                 const int* __restrict__ causal_flag) {
  __shared__ __align__(16) __bf16 kbuf[2][64 * 64];
  __shared__ __align__(16) __bf16 vbuf[2][64 * 64];
  __shared__ __align__(16) __bf16 pbuf[4][16 * 64];

  const int t = threadIdx.x;
  const int lane = t & 63;
  const int llo = lane & 15, lhi = lane >> 4;
  const int w = t >> 6;
  const int bh = blockIdx.y;
  const int causal = causal_flag[0];
  const int b = bh >> 4, h = bh & 15;

  const __bf16* Qb = Qh + (size_t)bh * SEQ * HD;
  const __bf16* Kb = Kh + (size_t)bh * SEQ * HD;
  const __bf16* Vb = Vt + (size_t)bh * HD * SEQ;

  const int sr = t >> 3;                              // staging row 0..31
  const int sce = (((t & 7) * 16) ^ ((sr & 7) << 4)) >> 1;  // swizzled src elem col
  const int swz = (llo & 7) << 4;

  char* const pw = (char*)&pbuf[w][0];

  for (int phase = 0; phase < 2; ++phase) {
    const int qt = phase ? (31 - (int)blockIdx.x) : (int)blockIdx.x;
    const int q0 = qt * 64;
    const int qw = q0 + w * 16;
    const int nt = causal ? (qt + 1) : (SEQ / 64);

    bf16x8 bQ[2];
#pragma unroll
    for (int ks = 0; ks < 2; ++ks)
      bQ[ks] = *(const bf16x8*)(Qb + (size_t)(qw + llo) * HD + ks * 32 + lhi * 8);

    float mrun = -1e30f, lrun = 0.f;
    f32x4 accO[4];
#pragma unroll
    for (int nf = 0; nf < 4; ++nf) accO[nf] = (f32x4){0.f, 0.f, 0.f, 0.f};

    // stage tile 0 -> buffer 0
    GLDS16(Kb + (size_t)sr * HD + sce,        (char*)&kbuf[0][0] + t * 16);
    GLDS16(Kb + (size_t)(32 + sr) * HD + sce, (char*)&kbuf[0][0] + 4096 + t * 16);
    GLDS16(Vb + (size_t)sr * SEQ + sce,       (char*)&vbuf[0][0] + t * 16);
    GLDS16(Vb + (size_t)(32 + sr) * SEQ + sce,(char*)&vbuf[0][0] + 4096 + t * 16);
    __syncthreads();
    int cur = 0;

    for (int tkv = 0; tkv < nt; ++tkv) {
      if (tkv + 1 < nt) {  // prefetch next tile into other buffer
        const int k0s = (tkv + 1) * 64;
        char* kd = (char*)&kbuf[cur ^ 1][0];
        char* vd = (char*)&vbuf[cur ^ 1][0];
        GLDS16(Kb + (size_t)(k0s + sr) * HD + sce,        kd + t * 16);
        GLDS16(Kb + (size_t)(k0s + 32 + sr) * HD + sce,   kd + 4096 + t * 16);
        GLDS16(Vb + (size_t)sr * SEQ + k0s + sce,         vd + t * 16);
        GLDS16(Vb + (size_t)(32 + sr) * SEQ + k0s + sce,  vd + 4096 + t * 16);
      }
      const int k0 = tkv * 64;
      char* kb = (char*)&kbuf[cur][0];
      char* vb = (char*)&vbuf[cur][0];

      // ---- S^T = K @ Q^T : lane owns q-row (qw+llo), kv = 16nf+4lhi+j
      f32x4 s[4];
#pragma unroll
      for (int nf = 0; nf < 4; ++nf) s[nf] = (f32x4){0.f, 0.f, 0.f, 0.f};
#pragma unroll
      for (int ks = 0; ks < 2; ++ks)
#pragma unroll
        for (int nf = 0; nf < 4; ++nf) {
          bf16x8 aK = *(const bf16x8*)(kb + (nf * 16 + llo) * 128 +
                                       ((ks * 64 + lhi * 16) ^ swz));
          s[nf] = __builtin_amdgcn_mfma_f32_16x16x32_bf16(aK, bQ[ks], s[nf], 0, 0, 0);
        }

      if (causal && tkv == qt) {
        const int qrow = qw + llo;
#pragma unroll
        for (int nf = 0; nf < 4; ++nf)
#pragma unroll
          for (int j = 0; j < 4; ++j)
            if (k0 + nf * 16 + lhi * 4 + j > qrow) s[nf][j] = -1e30f;
      }

      // ---- online softmax: in-lane over 16 + 2 shfl_xor across lhi groups
      float tm = -1e30f;
#pragma unroll
      for (int nf = 0; nf < 4; ++nf)
#pragma unroll
        for (int j = 0; j < 4; ++j) tm = fmaxf(tm, s[nf][j]);
      tm = fmaxf(tm, __shfl_xor(tm, 16, 64));
      tm = fmaxf(tm, __shfl_xor(tm, 32, 64));
      const float mnew = fmaxf(mrun, tm);
      const float corr = exp2f((mrun - mnew) * LOG2E);
      mrun = mnew;
      float ts = 0.f;
#pragma unroll
      for (int nf = 0; nf < 4; ++nf)
#pragma unroll
        for (int j = 0; j < 4; ++j) {
          const float p = exp2f((s[nf][j] - mnew) * LOG2E);
          s[nf][j] = p;
          ts += p;
        }
      ts += __shfl_xor(ts, 16, 64);
      ts += __shfl_xor(ts, 32, 64);
      lrun = lrun * corr + ts;

      // corr for accO rows (q = qw + lhi*4+j) lives at lane llo = lhi*4+j
      float corr_b[4];
#pragma unroll
      for (int j = 0; j < 4; ++j) corr_b[j] = __shfl(corr, lhi * 4 + j, 64);
#pragma unroll
      for (int nf = 0; nf < 4; ++nf)
#pragma unroll
        for (int j = 0; j < 4; ++j) accO[nf][j] *= corr_b[j];

      // ---- P -> LDS, packed 8B swizzled stores (row q=llo)
#pragma unroll
      for (int nf = 0; nf < 4; ++nf) {
        bf16x4 pk = {(__bf16)s[nf][0], (__bf16)s[nf][1], (__bf16)s[nf][2],
                     (__bf16)s[nf][3]};
        *(bf16x4*)(pw + llo * 128 + ((32 * nf + 8 * lhi) ^ swz)) = pk;
      }
      // ---- O += P @ V
#pragma unroll
      for (int ks2 = 0; ks2 < 2; ++ks2) {
        bf16x8 aP = *(const bf16x8*)(pw + llo * 128 + ((64 * ks2 + 16 * lhi) ^ swz));
#pragma unroll
        for (int nf = 0; nf < 4; ++nf) {
          bf16x8 bV = *(const bf16x8*)(vb + (nf * 16 + llo) * 128 +
                                       ((64 * ks2 + 16 * lhi) ^ swz));
          accO[nf] = __builtin_amdgcn_mfma_f32_16x16x32_bf16(aP, bV, accO[nf], 0, 0, 0);
        }
      }
      __syncthreads();   // staged buffer ready; all waves done with buf[cur]
      cur ^= 1;
    }

    // ---- normalize + store O as [b,s,h,d]
    const float linv = 1.f / lrun;
    float linv_b[4];
#pragma unroll
    for (int j = 0; j < 4; ++j) linv_b[j] = __shfl(linv, lhi * 4 + j, 64);
#pragma unroll
    for (int j = 0; j < 4; ++j) {
      const int srow = qw + lhi * 4 + j;
#pragma unroll
      for (int nf = 0; nf < 4; ++nf)
        O[((size_t)(b * SEQ + srow) * HEADS + h) * HD + nf * 16 + llo] =
            (__bf16)(accO[nf][j] * linv_b[j]);
    }
  }
}

// ---------------------------------------------------------- output projection
__global__ __launch_bounds__(256, 2)
void out_gemm_kernel(const __bf16* __restrict__ Oin, const __bf16* __restrict__ Wo,
                     const float* __restrict__ bo, float* __restrict__ out) {
  __shared__ __align__(16) __bf16 ldsA[128 * 32];
  __shared__ __align__(16) __bf16 ldsB[128 * 32];
  const int m0 = blockIdx.x * 128;
  const int n0 = blockIdx.y * 128;

  f32x4 acc[4][4];
  gemm_core_1024(Oin, Wo, m0, n0, ldsA, ldsB, acc);

  const int t = threadIdx.x;
  const int lane = t & 63;
  const int llo = lane & 15, lhi = lane >> 4;
  const int wid = t >> 6;
  const int wrow = (wid >> 1) * 64;
  const int wcol = (wid & 1) * 64;

#pragma unroll
  for (int nf = 0; nf < 4; ++nf) {
    const int col = n0 + wcol + nf * 16 + llo;
    const float bb = bo[col];
#pragma unroll
    for (int mf = 0; mf < 4; ++mf)
#pragma unroll
      for (int j = 0; j < 4; ++j) {
        const int row = m0 + wrow + mf * 16 + lhi * 4 + j;
        out[(size_t)row * NDIM + col] = acc[mf][nf][j] + bb;
      }
  }
}

// ------------------------------------------------------------------- launch
extern "C" void kernel_launch(void* const* d_in, const int* in_sizes, int n_in,
                              void* d_out, int out_size, void* d_ws, size_t ws_size,
                              hipStream_t stream) {
  const float* Q_in = (const float*)d_in[0];
  const float* K_in = (const float*)d_in[1];
  const float* V_in = (const float*)d_in[2];
  const float* Wq = (const float*)d_in[3];
  const float* bq = (const float*)d_in[4];
  const float* Wk = (const float*)d_in[5];
  const float* bk = (const float*)d_in[6];
  const float* Wv = (const float*)d_in[7];
  const float* bv = (const float*)d_in[8];
  const float* Wo = (const float*)d_in[9];
  const float* bo = (const float*)d_in[10];
  const int* causal = (const int*)d_in[11];
  float* out = (float*)d_out;

  char* p = (char*)d_ws;
  const size_t SZ_X = (size_t)MROWS * NDIM * 2;  // 8 MB
  const size_t SZ_W = (size_t)NDIM * NDIM * 2;   // 2 MB
  __bf16* bXq = (__bf16*)p; p += SZ_X;
  __bf16* bXk = (__bf16*)p; p += SZ_X;
  __bf16* bXv = (__bf16*)p; p += SZ_X;
  __bf16* bWq = (__bf16*)p; p += SZ_W;
  __bf16* bWk = (__bf16*)p; p += SZ_W;
  __bf16* bWv = (__bf16*)p; p += SZ_W;
  __bf16* bWo = (__bf16*)p; p += SZ_W;
  __bf16* Qh  = (__bf16*)p; p += SZ_X;
  __bf16* Kh  = (__bf16*)p; p += SZ_X;
  __bf16* Vt  = (__bf16*)p; p += SZ_X;
  __bf16* Obf = (__bf16*)p; p += SZ_X;

  const int XB = MROWS * NDIM / 1024;  // 4096 blocks
  const int WB = NDIM * NDIM / 1024;   // 1024 blocks
  cvt3_kernel<<<dim3(XB, 3), 256, 0, stream>>>(Q_in, K_in, V_in, bXq, bXk, bXv);
  cvt4_kernel<<<dim3(WB, 4), 256, 0, stream>>>(Wq, Wk, Wv, Wo, bWq, bWk, bWv, bWo);

  qkv_gemm_kernel<<<dim3(32, 24), 256, 0, stream>>>(bXq, bXk, bXv, bWq, bWk, bWv,
                                                    bq, bk, bv, Qh, Kh, Vt);
  attn_kernel<<<dim3(16, 32), 256, 0, stream>>>(Qh, Kh, Vt, Obf, causal);
  out_gemm_kernel<<<dim3(32, 8), 256, 0, stream>>>(Obf, bWo, bo, out);
}